// Round 1
// baseline (426.786 us; speedup 1.0000x reference)
//
#include <hip/hip_runtime.h>

typedef _Float16 f16;
typedef _Float16 f16x4 __attribute__((ext_vector_type(4)));
typedef _Float16 f16x8 __attribute__((ext_vector_type(8)));
typedef float    fx4   __attribute__((ext_vector_type(4)));

#define MODE_PROJ   0
#define MODE_PROJT  1
#define MODE_SCORES 2
#define MODE_PV     3

// Problem constants
constexpr int Bsz = 4;
constexpr int S   = 2048;
constexpr int DK  = 1024;

constexpr int BM = 128, BN = 128, BK = 32;
constexpr int LDSW = 40;  // 32 + 8 pad: 80 B rows, 16B-aligned, breaks pow2 bank stride

// NT GEMM: out[m,n] = sum_k A[m,k] * B[n,k]   (both operands K-major)
// 256 threads = 4 waves in a 2x2 grid; each wave computes 4x4 tiles of 16x16.
template<typename TA, int MODE>
__global__ __launch_bounds__(256, 2)
void gemm_kernel(const TA* __restrict__ A, const TA* __restrict__ B,
                 void* __restrict__ OutV, float* __restrict__ rowsum,
                 int lda, int ldb, int K, int ldo,
                 long aStride, long bStride, long oStride, int rsStride)
{
    __shared__ f16 lA[BM * LDSW];
    __shared__ f16 lB[BN * LDSW];

    const int tid = threadIdx.x;
    const int z   = blockIdx.z;
    A += (long)z * aStride;
    B += (long)z * bStride;
    if (rowsum) rowsum += (long)z * rsStride;

    const int row0 = blockIdx.y * BM;
    const int col0 = blockIdx.x * BN;

    const int lane = tid & 63;
    const int quad = lane >> 4;     // 0..3
    const int cn   = lane & 15;     // 0..15
    const int w    = tid >> 6;
    const int wm   = w >> 1;        // 0..1
    const int wn   = w & 1;         // 0..1

    fx4 acc[4][4];
    #pragma unroll
    for (int mt = 0; mt < 4; ++mt)
        #pragma unroll
        for (int nt = 0; nt < 4; ++nt)
            acc[mt][nt] = (fx4){0.f, 0.f, 0.f, 0.f};

    for (int k0 = 0; k0 < K; k0 += BK) {
        __syncthreads();
        if constexpr (sizeof(TA) == 4) {
            // fp32 input: load float4, convert to fp16, write 8B to LDS
            #pragma unroll
            for (int i = 0; i < 4; ++i) {
                int c = tid + i * 256;           // 1024 chunks of 4
                int r = c >> 3;
                int col = (c & 7) * 4;
                float4 fa = *(const float4*)(A + (size_t)(row0 + r) * lda + k0 + col);
                f16x4 ha = {(f16)fa.x, (f16)fa.y, (f16)fa.z, (f16)fa.w};
                *(f16x4*)&lA[r * LDSW + col] = ha;
                float4 fb = *(const float4*)(B + (size_t)(col0 + r) * ldb + k0 + col);
                f16x4 hb = {(f16)fb.x, (f16)fb.y, (f16)fb.z, (f16)fb.w};
                *(f16x4*)&lB[r * LDSW + col] = hb;
            }
        } else {
            // fp16 input: straight 16B copies
            #pragma unroll
            for (int i = 0; i < 2; ++i) {
                int c = tid + i * 256;           // 512 chunks of 8
                int r = c >> 2;
                int col = (c & 3) * 8;
                *(f16x8*)&lA[r * LDSW + col] =
                    *(const f16x8*)(A + (size_t)(row0 + r) * lda + k0 + col);
                *(f16x8*)&lB[r * LDSW + col] =
                    *(const f16x8*)(B + (size_t)(col0 + r) * ldb + k0 + col);
            }
        }
        __syncthreads();

        f16x8 af[4], bf[4];
        #pragma unroll
        for (int mt = 0; mt < 4; ++mt)
            af[mt] = *(const f16x8*)&lA[(wm * 64 + mt * 16 + cn) * LDSW + quad * 8];
        #pragma unroll
        for (int nt = 0; nt < 4; ++nt)
            bf[nt] = *(const f16x8*)&lB[(wn * 64 + nt * 16 + cn) * LDSW + quad * 8];
        #pragma unroll
        for (int mt = 0; mt < 4; ++mt)
            #pragma unroll
            for (int nt = 0; nt < 4; ++nt)
                acc[mt][nt] = __builtin_amdgcn_mfma_f32_16x16x32_f16(
                    af[mt], bf[nt], acc[mt][nt], 0, 0, 0);
    }

    // Epilogue. C/D layout: col = lane&15, row = quad*4 + reg (verified m89/m91).
    if constexpr (MODE == MODE_PROJ) {
        f16* O = (f16*)OutV + (long)z * oStride;
        #pragma unroll
        for (int mt = 0; mt < 4; ++mt) {
            int r0 = row0 + wm * 64 + mt * 16 + quad * 4;
            #pragma unroll
            for (int nt = 0; nt < 4; ++nt) {
                int c = col0 + wn * 64 + nt * 16 + cn;
                #pragma unroll
                for (int reg = 0; reg < 4; ++reg)
                    O[(size_t)(r0 + reg) * ldo + c] = (f16)acc[mt][nt][reg];
            }
        }
    } else if constexpr (MODE == MODE_PROJT) {
        // transposed store: O[e][s], ld = S. 4 consecutive s per lane -> 8B store.
        f16* O = (f16*)OutV + (long)z * oStride;
        #pragma unroll
        for (int mt = 0; mt < 4; ++mt) {
            int r0 = row0 + wm * 64 + mt * 16 + quad * 4;
            #pragma unroll
            for (int nt = 0; nt < 4; ++nt) {
                int c = col0 + wn * 64 + nt * 16 + cn;
                f16x4 h = {(f16)acc[mt][nt][0], (f16)acc[mt][nt][1],
                           (f16)acc[mt][nt][2], (f16)acc[mt][nt][3]};
                *(f16x4*)&O[(size_t)c * S + r0] = h;
            }
        }
    } else if constexpr (MODE == MODE_SCORES) {
        f16* O = (f16*)OutV + (long)z * oStride;
        const float scale = 0.03125f;  // 1/sqrt(1024)
        float rs[4][4];
        #pragma unroll
        for (int mt = 0; mt < 4; ++mt)
            #pragma unroll
            for (int reg = 0; reg < 4; ++reg) rs[mt][reg] = 0.f;
        #pragma unroll
        for (int mt = 0; mt < 4; ++mt) {
            int r0 = row0 + wm * 64 + mt * 16 + quad * 4;
            #pragma unroll
            for (int nt = 0; nt < 4; ++nt) {
                int c = col0 + wn * 64 + nt * 16 + cn;
                #pragma unroll
                for (int reg = 0; reg < 4; ++reg) {
                    float v = __expf(acc[mt][nt][reg] * scale);
                    rs[mt][reg] += v;
                    O[(size_t)(r0 + reg) * ldo + c] = (f16)v;
                }
            }
        }
        // reduce rs across the 16 column-lanes, one atomic per row
        #pragma unroll
        for (int mt = 0; mt < 4; ++mt) {
            int r0 = row0 + wm * 64 + mt * 16 + quad * 4;
            #pragma unroll
            for (int reg = 0; reg < 4; ++reg) {
                float v = rs[mt][reg];
                v += __shfl_xor(v, 1);
                v += __shfl_xor(v, 2);
                v += __shfl_xor(v, 4);
                v += __shfl_xor(v, 8);
                if (cn == 0) atomicAdd(&rowsum[r0 + reg], v);
            }
        }
    } else {  // MODE_PV
        float* O = (float*)OutV + (long)z * oStride;
        #pragma unroll
        for (int mt = 0; mt < 4; ++mt) {
            int r0 = row0 + wm * 64 + mt * 16 + quad * 4;
            fx4 rsv = *(const fx4*)&rowsum[r0];
            fx4 inv = {1.f / rsv[0], 1.f / rsv[1], 1.f / rsv[2], 1.f / rsv[3]};
            #pragma unroll
            for (int nt = 0; nt < 4; ++nt) {
                int c = col0 + wn * 64 + nt * 16 + cn;
                #pragma unroll
                for (int reg = 0; reg < 4; ++reg)
                    O[(size_t)(r0 + reg) * ldo + c] = acc[mt][nt][reg] * inv[reg];
            }
        }
    }
}

extern "C" void kernel_launch(void* const* d_in, const int* in_sizes, int n_in,
                              void* d_out, int out_size, void* d_ws, size_t ws_size,
                              hipStream_t stream) {
    const float* q  = (const float*)d_in[0];
    const float* k  = (const float*)d_in[1];
    const float* v  = (const float*)d_in[2];
    const float* wq = (const float*)d_in[3];
    const float* wk = (const float*)d_in[4];
    const float* wv = (const float*)d_in[5];
    float* out = (float*)d_out;

    char* ws = (char*)d_ws;
    f16*   qp     = (f16*)(ws);                          // 16 MB [B*S, DK]
    f16*   kp     = (f16*)(ws + ((size_t)16 << 20));     // 16 MB [B*S, DK]
    f16*   vpT    = (f16*)(ws + ((size_t)32 << 20));     // 16 MB [B][DK][S]
    f16*   E      = (f16*)(ws + ((size_t)48 << 20));     // 32 MB [B][S][S]
    float* rowsum = (float*)(ws + ((size_t)80 << 20));   // 32 KB [B][S]

    hipMemsetAsync(rowsum, 0, (size_t)Bsz * S * sizeof(float), stream);

    dim3 blk(256);
    const long SD = (long)S * DK;   // 2M elements
    const long SS = (long)S * S;    // 4M elements

    // q/k projections: [S,DK] x [DK,DK]^T per batch -> fp16
    gemm_kernel<float, MODE_PROJ><<<dim3(DK / BN, S / BM, Bsz), blk, 0, stream>>>(
        q, wq, qp, nullptr, DK, DK, DK, DK, SD, 0, SD, 0);
    gemm_kernel<float, MODE_PROJ><<<dim3(DK / BN, S / BM, Bsz), blk, 0, stream>>>(
        k, wk, kp, nullptr, DK, DK, DK, DK, SD, 0, SD, 0);
    // v projection with transposed store -> vpT[b][e][s]
    gemm_kernel<float, MODE_PROJT><<<dim3(DK / BN, S / BM, Bsz), blk, 0, stream>>>(
        v, wv, vpT, nullptr, DK, DK, DK, 0, SD, 0, SD, 0);
    // scores: E[b][q][kk] = exp(qp.kp/32), rowsum accumulated
    gemm_kernel<f16, MODE_SCORES><<<dim3(S / BN, S / BM, Bsz), blk, 0, stream>>>(
        qp, kp, E, rowsum, DK, DK, DK, S, SD, SD, SS, S);
    // PV: out[b][q][e] = (E @ vpT^T) / rowsum
    gemm_kernel<f16, MODE_PV><<<dim3(DK / BN, S / BM, Bsz), blk, 0, stream>>>(
        E, vpT, out, rowsum, S, S, S, DK, SS, SD, SD, S);
}

// Round 3
// 335.023 us; speedup vs baseline: 1.2739x; 1.2739x over previous
//
#include <hip/hip_runtime.h>

typedef _Float16 f16;
typedef _Float16 f16x4 __attribute__((ext_vector_type(4)));
typedef _Float16 f16x8 __attribute__((ext_vector_type(8)));
typedef float    fx4   __attribute__((ext_vector_type(4)));

#define MODE_PROJ   0
#define MODE_SCORES 1
#define MODE_PV     2

constexpr int Bsz = 4;
constexpr int S   = 2048;
constexpr int DK  = 1024;
constexpr int BM = 128, BN = 128, BK = 32;
constexpr long SD   = (long)S * DK;          // 2M elems
constexpr long SS   = (long)S * S;           // 4M elems
constexpr long BIGN = (long)Bsz * S * DK;    // 8M elems

// async global->LDS, 16B per lane; LDS dest must be wave-uniform (HW adds lane*16)
__device__ __forceinline__ void glds16(const f16* g, f16* l) {
    __builtin_amdgcn_global_load_lds(
        (const __attribute__((address_space(1))) void*)g,
        (__attribute__((address_space(3))) void*)l, 16, 0, 0);
}

// In-place fp32 -> fp16 conversion. Each block owns a 2048-elem fp32 region
// (2 rows of 1024 = 8192 bytes) and writes the fp16 result into the FIRST HALF
// (4096 bytes) of its own region (no cross-block WAR).
// Pair-packed layout for row r, col c (f16 element index):
//   idx = (r>>1)*4096 + (r&1)*1024 + c        // region stride = 4096 f16 = 8192 B
__global__ __launch_bounds__(256)
void convert_kernel(const float* q, const float* k, const float* v,
                    const float* wq, const float* wk, const float* wv)
{
    int bx = blockIdx.x;
    const float* src;
    int blk;
    if (bx < 12288) {                     // 3 big tensors, 4096 blocks each
        int t = bx >> 12; blk = bx & 4095;
        src = (t == 0) ? q : (t == 1) ? k : v;
    } else {                              // 3 weights, 512 blocks each
        int u = bx - 12288;
        int t = u >> 9; blk = u & 511;
        src = (t == 0) ? wq : (t == 1) ? wk : wv;
    }
    size_t off = (size_t)blk * 2048 + (size_t)threadIdx.x * 8;
    float4 f0 = *(const float4*)(src + off);
    float4 f1 = *(const float4*)(src + off + 4);
    __syncthreads();   // all reads of this block's region complete before any write
    f16x8 h = {(f16)f0.x, (f16)f0.y, (f16)f0.z, (f16)f0.w,
               (f16)f1.x, (f16)f1.y, (f16)f1.z, (f16)f1.w};
    *(f16x8*)((char*)src + (size_t)blk * 8192 + (size_t)threadIdx.x * 16) = h;
}

// pair-packed f16 element index for (row, col)
__device__ __forceinline__ size_t pp(int r, int c) {
    return ((size_t)(r >> 1) << 12) + ((r & 1) << 10) + c;
}

// NT GEMM, all-fp16 operands, global_load_lds staging, 128x128x32 tiles,
// 4 waves (2x2), 4x4 16x16x32 MFMA tiles per wave.
template<int MODE>
__global__ __launch_bounds__(256, 4)
void gemm_kernel(const f16* A0, const f16* A1, const f16* A2,
                 const f16* B0, const f16* B1, const f16* B2,
                 void* O0, void* O1, float* rowsum,
                 int lda, int ldb, int K, int ldo)
{
    __shared__ f16 lA[BM * BK];   // 8 KB, unpadded (glds lane order)
    __shared__ f16 lB[BN * BK];

    const int tid = threadIdx.x;
    const int z   = blockIdx.z;
    const int row0 = blockIdx.y * BM;
    const int col0 = blockIdx.x * BN;
    const int lane = tid & 63;
    const int quad = lane >> 4;
    const int cn   = lane & 15;
    const int w    = tid >> 6;
    const int wm   = w >> 1;
    const int wn   = w & 1;

    const f16 *Ap, *Bp;
    if constexpr (MODE == MODE_PROJ) {
        Ap = (z == 0) ? A0 : (z == 1) ? A1 : A2;      // pair-packed q/k/v
        Bp = (z == 0) ? B0 : (z == 1) ? B1 : B2;      // pair-packed weights
    } else if constexpr (MODE == MODE_SCORES) {
        Ap = A0 + (long)z * SD;  Bp = B0 + (long)z * SD;
        rowsum += (long)z * S;
    } else {
        Ap = A0 + (long)z * SS;  Bp = B0 + (long)z * SD;
        rowsum += (long)z * S;
    }

    fx4 acc[4][4];
    #pragma unroll
    for (int mt = 0; mt < 4; ++mt)
        #pragma unroll
        for (int nt = 0; nt < 4; ++nt)
            acc[mt][nt] = (fx4){0.f, 0.f, 0.f, 0.f};

    const int lr = lane >> 2;          // 0..15: row within 16-row chunk
    const int lc = (lane & 3) * 8;     // 0/8/16/24: col

    for (int k0 = 0; k0 < K; k0 += BK) {
        __syncthreads();
        #pragma unroll
        for (int i = 0; i < 2; ++i) {
            int rb = w * 32 + i * 16;  // wave-uniform
            if constexpr (MODE == MODE_PROJ) {
                int ra  = row0 + rb + lr;
                int rbt = col0 + rb + lr;
                glds16(Ap + pp(ra,  k0 + lc), &lA[rb * BK]);
                glds16(Bp + pp(rbt, k0 + lc), &lB[rb * BK]);
            } else {
                glds16(Ap + (size_t)(row0 + rb + lr) * lda + k0 + lc, &lA[rb * BK]);
                glds16(Bp + (size_t)(col0 + rb + lr) * ldb + k0 + lc, &lB[rb * BK]);
            }
        }
        __syncthreads();

        f16x8 af[4], bf[4];
        #pragma unroll
        for (int mt = 0; mt < 4; ++mt)
            af[mt] = *(const f16x8*)&lA[(wm * 64 + mt * 16 + cn) * BK + quad * 8];
        #pragma unroll
        for (int nt = 0; nt < 4; ++nt)
            bf[nt] = *(const f16x8*)&lB[(wn * 64 + nt * 16 + cn) * BK + quad * 8];
        #pragma unroll
        for (int mt = 0; mt < 4; ++mt)
            #pragma unroll
            for (int nt = 0; nt < 4; ++nt)
                acc[mt][nt] = __builtin_amdgcn_mfma_f32_16x16x32_f16(
                    af[mt], bf[nt], acc[mt][nt], 0, 0, 0);
    }

    // C/D layout: col = lane&15, row = quad*4 + reg
    if constexpr (MODE == MODE_PROJ) {
        if (z < 2) {
            f16* O = (f16*)O0 + (long)z * BIGN;   // qp / kp (contiguous in ws)
            #pragma unroll
            for (int mt = 0; mt < 4; ++mt) {
                int r0 = row0 + wm * 64 + mt * 16 + quad * 4;
                #pragma unroll
                for (int nt = 0; nt < 4; ++nt) {
                    int c = col0 + wn * 64 + nt * 16 + cn;
                    #pragma unroll
                    for (int reg = 0; reg < 4; ++reg)
                        O[(size_t)(r0 + reg) * DK + c] = (f16)acc[mt][nt][reg];
                }
            }
        } else {
            // v: transposed store -> vpT[b][e][s]
            #pragma unroll
            for (int mt = 0; mt < 4; ++mt) {
                int r0 = row0 + wm * 64 + mt * 16 + quad * 4;
                int b  = r0 >> 11;
                int s  = r0 & 2047;                    // multiple of 4
                f16* O = (f16*)O1 + (long)b * SD;
                #pragma unroll
                for (int nt = 0; nt < 4; ++nt) {
                    int c = col0 + wn * 64 + nt * 16 + cn;
                    f16x4 h = {(f16)acc[mt][nt][0], (f16)acc[mt][nt][1],
                               (f16)acc[mt][nt][2], (f16)acc[mt][nt][3]};
                    *(f16x4*)&O[(size_t)c * S + s] = h;
                }
            }
        }
    } else if constexpr (MODE == MODE_SCORES) {
        f16* O = (f16*)O0 + (long)z * SS;
        const float scale = 0.03125f;  // 1/sqrt(1024)
        float rs[4][4];
        #pragma unroll
        for (int mt = 0; mt < 4; ++mt)
            #pragma unroll
            for (int reg = 0; reg < 4; ++reg) rs[mt][reg] = 0.f;
        #pragma unroll
        for (int mt = 0; mt < 4; ++mt) {
            int r0 = row0 + wm * 64 + mt * 16 + quad * 4;
            #pragma unroll
            for (int nt = 0; nt < 4; ++nt) {
                int c = col0 + wn * 64 + nt * 16 + cn;
                #pragma unroll
                for (int reg = 0; reg < 4; ++reg) {
                    float vv = __expf(acc[mt][nt][reg] * scale);
                    rs[mt][reg] += vv;
                    O[(size_t)(r0 + reg) * ldo + c] = (f16)vv;
                }
            }
        }
        #pragma unroll
        for (int mt = 0; mt < 4; ++mt) {
            int r0 = row0 + wm * 64 + mt * 16 + quad * 4;
            #pragma unroll
            for (int reg = 0; reg < 4; ++reg) {
                float vv = rs[mt][reg];
                vv += __shfl_xor(vv, 1);
                vv += __shfl_xor(vv, 2);
                vv += __shfl_xor(vv, 4);
                vv += __shfl_xor(vv, 8);
                if (cn == 0) atomicAdd(&rowsum[r0 + reg], vv);
            }
        }
    } else {  // MODE_PV
        float* O = (float*)O0 + (long)z * SD;
        #pragma unroll
        for (int mt = 0; mt < 4; ++mt) {
            int r0 = row0 + wm * 64 + mt * 16 + quad * 4;
            fx4 rsv = *(const fx4*)&rowsum[r0];
            fx4 inv = {1.f / rsv[0], 1.f / rsv[1], 1.f / rsv[2], 1.f / rsv[3]};
            #pragma unroll
            for (int nt = 0; nt < 4; ++nt) {
                int c = col0 + wn * 64 + nt * 16 + cn;
                #pragma unroll
                for (int reg = 0; reg < 4; ++reg)
                    O[(size_t)(r0 + reg) * ldo + c] = acc[mt][nt][reg] * inv[reg];
            }
        }
    }
}

extern "C" void kernel_launch(void* const* d_in, const int* in_sizes, int n_in,
                              void* d_out, int out_size, void* d_ws, size_t ws_size,
                              hipStream_t stream) {
    const float* q  = (const float*)d_in[0];
    const float* k  = (const float*)d_in[1];
    const float* v  = (const float*)d_in[2];
    const float* wq = (const float*)d_in[3];
    const float* wk = (const float*)d_in[4];
    const float* wv = (const float*)d_in[5];
    float* out = (float*)d_out;

    char* ws = (char*)d_ws;
    f16*   qp     = (f16*)(ws);                          // 16 MB [8192, 1024]
    f16*   kp     = (f16*)(ws + ((size_t)16 << 20));     // 16 MB [8192, 1024]
    f16*   vpT    = (f16*)(ws + ((size_t)32 << 20));     // 16 MB [B][DK][S]
    f16*   E      = (f16*)(ws + ((size_t)48 << 20));     // 32 MB [B][S][S]
    float* rowsum = (float*)(ws + ((size_t)80 << 20));   // 32 KB [B][S]

    hipMemsetAsync(rowsum, 0, (size_t)Bsz * S * sizeof(float), stream);

    // in-place convert all inputs to fp16 (pair-packed, region stride 8192 B)
    convert_kernel<<<13824, 256, 0, stream>>>(q, k, v, wq, wk, wv);

    const f16* qh  = (const f16*)q;
    const f16* kh  = (const f16*)k;
    const f16* vh  = (const f16*)v;
    const f16* wqh = (const f16*)wq;
    const f16* wkh = (const f16*)wk;
    const f16* wvh = (const f16*)wv;

    dim3 blk(256);
    // fused projections: z=0 -> qp, z=1 -> kp, z=2 -> vpT (transposed)
    gemm_kernel<MODE_PROJ><<<dim3(DK / BN, (Bsz * S) / BM, 3), blk, 0, stream>>>(
        qh, kh, vh, wqh, wkh, wvh, qp, vpT, nullptr, DK, DK, DK, DK);
    // scores: E = exp(qp.kp/32), rowsum accumulated
    gemm_kernel<MODE_SCORES><<<dim3(S / BN, S / BM, Bsz), blk, 0, stream>>>(
        qp, nullptr, nullptr, kp, nullptr, nullptr, E, nullptr, rowsum,
        DK, DK, DK, S);
    // PV: out = (E @ vpT^T) / rowsum
    gemm_kernel<MODE_PV><<<dim3(DK / BN, S / BM, Bsz), blk, 0, stream>>>(
        E, nullptr, nullptr, vpT, nullptr, nullptr, out, nullptr, rowsum,
        S, S, S, DK);
}

// Round 4
// 298.804 us; speedup vs baseline: 1.4283x; 1.1212x over previous
//
#include <hip/hip_runtime.h>

typedef _Float16 f16;
typedef _Float16 f16x4 __attribute__((ext_vector_type(4)));
typedef _Float16 f16x8 __attribute__((ext_vector_type(8)));
typedef float    fx4   __attribute__((ext_vector_type(4)));

#define MODE_PROJ   0
#define MODE_SCORES 1
#define MODE_PV     2

constexpr int Bsz = 4;
constexpr int S   = 2048;
constexpr int DK  = 1024;
constexpr int BM = 128, BN = 128, BK = 64;
constexpr long SD   = (long)S * DK;          // 2M elems
constexpr long SS   = (long)S * S;           // 4M elems
constexpr long BIGN = (long)Bsz * S * DK;    // 8M elems

// async global->LDS, 16B per lane; LDS dest wave-uniform (HW adds lane*16)
__device__ __forceinline__ void glds16(const f16* g, f16* l) {
    __builtin_amdgcn_global_load_lds(
        (const __attribute__((address_space(1))) void*)g,
        (__attribute__((address_space(3))) void*)l, 16, 0, 0);
}

// In-place fp32 -> fp16 conversion, pair-packed:
//   f16 idx = (r>>1)*4096 + (r&1)*1024 + c   (region stride 4096 f16 = 8192 B)
__global__ __launch_bounds__(256)
void convert_kernel(const float* q, const float* k, const float* v,
                    const float* wq, const float* wk, const float* wv)
{
    int bx = blockIdx.x;
    const float* src;
    int blk;
    if (bx < 12288) {
        int t = bx >> 12; blk = bx & 4095;
        src = (t == 0) ? q : (t == 1) ? k : v;
    } else {
        int u = bx - 12288;
        int t = u >> 9; blk = u & 511;
        src = (t == 0) ? wq : (t == 1) ? wk : wv;
    }
    size_t off = (size_t)blk * 2048 + (size_t)threadIdx.x * 8;
    float4 f0 = *(const float4*)(src + off);
    float4 f1 = *(const float4*)(src + off + 4);
    __syncthreads();
    f16x8 h = {(f16)f0.x, (f16)f0.y, (f16)f0.z, (f16)f0.w,
               (f16)f1.x, (f16)f1.y, (f16)f1.z, (f16)f1.w};
    *(f16x8*)((char*)src + (size_t)blk * 8192 + (size_t)threadIdx.x * 16) = h;
}

__device__ __forceinline__ size_t pp(int r, int c) {
    return ((size_t)(r >> 1) << 12) + ((r & 1) << 10) + c;
}

// NT GEMM, fp16, glds16 staging with XOR bank swizzle, 128x128x64 tiles.
// XCD swizzle: 1D grid x; row = id & (R-1), col = id >> lgR -> blocks sharing an
// A row-band have ids = row (mod 8) -> same XCD -> band L2-resident.
template<int MODE>
__global__ __launch_bounds__(256, 4)
void gemm_kernel(const f16* A0, const f16* A1, const f16* A2,
                 const f16* B0, const f16* B1, const f16* B2,
                 void* O0, void* O1, float* rowsum,
                 int lda, int ldb, int K, int ldo)
{
    __shared__ f16 lA[BM * BK];   // 16 KB
    __shared__ f16 lB[BN * BK];   // 16 KB

    const int tid = threadIdx.x;
    const int id  = blockIdx.x;
    const int z   = blockIdx.y;
    int row0, col0;
    if constexpr (MODE == MODE_PROJ) { row0 = (id & 63) * BM; col0 = (id >> 6) * BN; }
    else                             { row0 = (id & 15) * BM; col0 = (id >> 4) * BN; }

    const int lane = tid & 63;
    const int quad = lane >> 4;
    const int cn   = lane & 15;
    const int w    = tid >> 6;
    const int wm   = w >> 1;
    const int wn   = w & 1;

    const f16 *Ap, *Bp;
    if constexpr (MODE == MODE_PROJ) {
        Ap = (z == 0) ? A0 : (z == 1) ? A1 : A2;
        Bp = (z == 0) ? B0 : (z == 1) ? B1 : B2;
    } else if constexpr (MODE == MODE_SCORES) {
        Ap = A0 + (long)z * SD;  Bp = B0 + (long)z * SD;
        rowsum += (long)z * S;
    } else {
        Ap = A0 + (long)z * SS;  Bp = B0 + (long)z * SD;
        rowsum += (long)z * S;
    }

    fx4 acc[4][4];
    #pragma unroll
    for (int mt = 0; mt < 4; ++mt)
        #pragma unroll
        for (int nt = 0; nt < 4; ++nt)
            acc[mt][nt] = (fx4){0.f, 0.f, 0.f, 0.f};

    // staging lane map: 8 rows x 8 chunks of 16B; fetch XOR-permuted chunk so
    // LDS physical chunk (lane&7) holds global chunk (lane&7)^(row&7)
    const int lr8 = lane >> 3;            // 0..7 row within 8-row group
    const int swc = (lane & 7) ^ lr8;     // swizzled global chunk
    const int lcS = swc << 3;             // f16 col within BK

    for (int k0 = 0; k0 < K; k0 += BK) {
        __syncthreads();
        #pragma unroll
        for (int i = 0; i < 4; ++i) {
            int rb = w * 32 + i * 8;      // wave-uniform row base
            if constexpr (MODE == MODE_PROJ) {
                glds16(Ap + pp(row0 + rb + lr8, k0 + lcS), &lA[rb * BK]);
                glds16(Bp + pp(col0 + rb + lr8, k0 + lcS), &lB[rb * BK]);
            } else {
                glds16(Ap + (size_t)(row0 + rb + lr8) * lda + k0 + lcS, &lA[rb * BK]);
                glds16(Bp + (size_t)(col0 + rb + lr8) * ldb + k0 + lcS, &lB[rb * BK]);
            }
        }
        __syncthreads();

        #pragma unroll
        for (int kh = 0; kh < 2; ++kh) {
            f16x8 af[4], bf[4];
            #pragma unroll
            for (int mt = 0; mt < 4; ++mt) {
                int r = wm * 64 + mt * 16 + cn;
                int ch = ((kh << 2) | quad) ^ (r & 7);
                af[mt] = *(const f16x8*)&lA[r * BK + ch * 8];
            }
            #pragma unroll
            for (int nt = 0; nt < 4; ++nt) {
                int r = wn * 64 + nt * 16 + cn;
                int ch = ((kh << 2) | quad) ^ (r & 7);
                bf[nt] = *(const f16x8*)&lB[r * BK + ch * 8];
            }
            #pragma unroll
            for (int mt = 0; mt < 4; ++mt)
                #pragma unroll
                for (int nt = 0; nt < 4; ++nt)
                    acc[mt][nt] = __builtin_amdgcn_mfma_f32_16x16x32_f16(
                        af[mt], bf[nt], acc[mt][nt], 0, 0, 0);
        }
    }

    // C/D layout: col = lane&15, row = quad*4 + reg
    if constexpr (MODE == MODE_PROJ) {
        if (z < 2) {
            f16* O = (f16*)O0 + (long)z * BIGN;   // qp / kp
            #pragma unroll
            for (int mt = 0; mt < 4; ++mt) {
                int r0 = row0 + wm * 64 + mt * 16 + quad * 4;
                #pragma unroll
                for (int nt = 0; nt < 4; ++nt) {
                    int c = col0 + wn * 64 + nt * 16 + cn;
                    #pragma unroll
                    for (int reg = 0; reg < 4; ++reg)
                        O[(size_t)(r0 + reg) * DK + c] = (f16)acc[mt][nt][reg];
                }
            }
        } else {
            // v: transposed store -> vpT[b][e][s]
            #pragma unroll
            for (int mt = 0; mt < 4; ++mt) {
                int r0 = row0 + wm * 64 + mt * 16 + quad * 4;
                int b  = r0 >> 11;
                int s  = r0 & 2047;
                f16* O = (f16*)O1 + (long)b * SD;
                #pragma unroll
                for (int nt = 0; nt < 4; ++nt) {
                    int c = col0 + wn * 64 + nt * 16 + cn;
                    f16x4 h = {(f16)acc[mt][nt][0], (f16)acc[mt][nt][1],
                               (f16)acc[mt][nt][2], (f16)acc[mt][nt][3]};
                    *(f16x4*)&O[(size_t)c * S + s] = h;
                }
            }
        }
    } else if constexpr (MODE == MODE_SCORES) {
        f16* O = (f16*)O0 + (long)z * SS;
        const float sl2e = 0.03125f * 1.44269504f;  // (1/32)*log2(e)
        float rs[4][4];
        #pragma unroll
        for (int mt = 0; mt < 4; ++mt)
            #pragma unroll
            for (int reg = 0; reg < 4; ++reg) rs[mt][reg] = 0.f;
        #pragma unroll
        for (int mt = 0; mt < 4; ++mt) {
            int r0 = row0 + wm * 64 + mt * 16 + quad * 4;
            #pragma unroll
            for (int nt = 0; nt < 4; ++nt) {
                int c = col0 + wn * 64 + nt * 16 + cn;
                #pragma unroll
                for (int reg = 0; reg < 4; ++reg) {
                    float vv = exp2f(acc[mt][nt][reg] * sl2e);
                    rs[mt][reg] += vv;
                    O[(size_t)(r0 + reg) * ldo + c] = (f16)vv;
                }
            }
        }
        #pragma unroll
        for (int mt = 0; mt < 4; ++mt) {
            int r0 = row0 + wm * 64 + mt * 16 + quad * 4;
            #pragma unroll
            for (int reg = 0; reg < 4; ++reg) {
                float vv = rs[mt][reg];
                vv += __shfl_xor(vv, 1);
                vv += __shfl_xor(vv, 2);
                vv += __shfl_xor(vv, 4);
                vv += __shfl_xor(vv, 8);
                if (cn == 0) atomicAdd(&rowsum[r0 + reg], vv);
            }
        }
    } else {  // MODE_PV
        float* O = (float*)O0 + (long)z * SD;
        #pragma unroll
        for (int mt = 0; mt < 4; ++mt) {
            int r0 = row0 + wm * 64 + mt * 16 + quad * 4;
            fx4 rsv = *(const fx4*)&rowsum[r0];
            fx4 inv = {1.f / rsv[0], 1.f / rsv[1], 1.f / rsv[2], 1.f / rsv[3]};
            #pragma unroll
            for (int nt = 0; nt < 4; ++nt) {
                int c = col0 + wn * 64 + nt * 16 + cn;
                #pragma unroll
                for (int reg = 0; reg < 4; ++reg)
                    O[(size_t)(r0 + reg) * ldo + c] = acc[mt][nt][reg] * inv[reg];
            }
        }
    }
}

extern "C" void kernel_launch(void* const* d_in, const int* in_sizes, int n_in,
                              void* d_out, int out_size, void* d_ws, size_t ws_size,
                              hipStream_t stream) {
    const float* q  = (const float*)d_in[0];
    const float* k  = (const float*)d_in[1];
    const float* v  = (const float*)d_in[2];
    const float* wq = (const float*)d_in[3];
    const float* wk = (const float*)d_in[4];
    const float* wv = (const float*)d_in[5];
    float* out = (float*)d_out;

    char* ws = (char*)d_ws;
    f16*   qp     = (f16*)(ws);                          // 16 MB [8192, 1024]
    f16*   kp     = (f16*)(ws + ((size_t)16 << 20));     // 16 MB [8192, 1024]
    f16*   vpT    = (f16*)(ws + ((size_t)32 << 20));     // 16 MB [B][DK][S]
    f16*   E      = (f16*)(ws + ((size_t)48 << 20));     // 32 MB [B][S][S]
    float* rowsum = (float*)(ws + ((size_t)80 << 20));   // 32 KB [B][S]

    hipMemsetAsync(rowsum, 0, (size_t)Bsz * S * sizeof(float), stream);

    convert_kernel<<<13824, 256, 0, stream>>>(q, k, v, wq, wk, wv);

    const f16* qh  = (const f16*)q;
    const f16* kh  = (const f16*)k;
    const f16* vh  = (const f16*)v;
    const f16* wqh = (const f16*)wq;
    const f16* wkh = (const f16*)wk;
    const f16* wvh = (const f16*)wv;

    dim3 blk(256);
    // fused projections: y=0 -> qp, y=1 -> kp, y=2 -> vpT (transposed)
    gemm_kernel<MODE_PROJ><<<dim3(512, 3), blk, 0, stream>>>(
        qh, kh, vh, wqh, wkh, wvh, qp, vpT, nullptr, DK, DK, DK, DK);
    // scores: E = exp(qp.kp/32), rowsum accumulated
    gemm_kernel<MODE_SCORES><<<dim3(256, 4), blk, 0, stream>>>(
        qp, nullptr, nullptr, kp, nullptr, nullptr, E, nullptr, rowsum,
        DK, DK, DK, S);
    // PV: out = (E @ vpT^T) / rowsum
    gemm_kernel<MODE_PV><<<dim3(128, 4), blk, 0, stream>>>(
        E, nullptr, nullptr, vpT, nullptr, nullptr, out, nullptr, rowsum,
        S, S, S, DK);
}